// Round 1
// baseline (804.629 us; speedup 1.0000x reference)
//
#include <hip/hip_runtime.h>

#define NN 100000
#define NE 1000000
#define D  64

// ---- degree ----
__global__ void k_init_deg(float* __restrict__ deg) {
    int n = blockIdx.x * blockDim.x + threadIdx.x;
    if (n < NN) deg[n] = 1.0f;  // self-loop
}

__global__ void k_count_deg(const int* __restrict__ dst, float* __restrict__ deg) {
    int e = blockIdx.x * blockDim.x + threadIdx.x;
    if (e < NE) atomicAdd(&deg[dst[e]], 1.0f);
}

__global__ void k_dinv(float* __restrict__ deg) {
    int n = blockIdx.x * blockDim.x + threadIdx.x;
    if (n < NN) deg[n] = rsqrtf(deg[n]);  // deg >= 1 always
}

// ---- propagation: out = D^{-1/2}(A+I)D^{-1/2} @ in ----
// self-loop term doubles as buffer init (no separate zeroing needed)
__global__ void k_prop_init(const float* __restrict__ in,
                            const float* __restrict__ dinv,
                            float* __restrict__ out) {
    int i = blockIdx.x * blockDim.x + threadIdx.x;
    if (i < NN * D) {
        int n = i >> 6;
        float di = dinv[n];
        out[i] = di * di * in[i];
    }
}

// one 64-lane wave per edge; lane = feature index
__global__ __launch_bounds__(256) void k_prop_edges(const float* __restrict__ in,
                                                    const int* __restrict__ src,
                                                    const int* __restrict__ dst,
                                                    const float* __restrict__ dinv,
                                                    float* __restrict__ out) {
    int t = blockIdx.x * blockDim.x + threadIdx.x;
    int e = t >> 6;
    int f = t & 63;
    if (e < NE) {
        int s = src[e];
        int d = dst[e];
        float w = dinv[s] * dinv[d];
        atomicAdd(&out[d * D + f], w * in[s * D + f]);
    }
}

// ---- linear: out[n,o] = sum_i in[n,i] * W[o,i] + b[o] ----
__global__ __launch_bounds__(256) void k_linear(const float* __restrict__ in,
                                                const float* __restrict__ W,
                                                const float* __restrict__ bias,
                                                float* __restrict__ out) {
    __shared__ float Wt[64 * 65];    // Wt[i*65+o] = W[o*64+i]  (padded: conflict-free)
    __shared__ float rows[4][64];    // per-wave row staging
    const int tid = threadIdx.x;

    for (int m = tid; m < 64 * 64; m += 256) {
        int o = m >> 6, i = m & 63;
        Wt[i * 65 + o] = W[m];
    }
    __syncthreads();

    const int wave = tid >> 6;
    const int lane = tid & 63;
    const float bo = bias[lane];

    for (int base = blockIdx.x * 4; base < NN; base += gridDim.x * 4) {
        int n = base + wave;
        if (n < NN) {
            rows[wave][lane] = in[n * D + lane];   // wave-internal: lockstep, no barrier needed
            float acc = bo;
            #pragma unroll
            for (int i = 0; i < 64; ++i)
                acc = fmaf(rows[wave][i], Wt[i * 65 + lane], acc);
            out[n * D + lane] = acc;
        }
    }
}

extern "C" void kernel_launch(void* const* d_in, const int* in_sizes, int n_in,
                              void* d_out, int out_size, void* d_ws, size_t ws_size,
                              hipStream_t stream) {
    const float* x   = (const float*)d_in[0];
    const int*   ei  = (const int*)d_in[1];
    const float* W   = (const float*)d_in[2];
    const float* b   = (const float*)d_in[3];
    float* out = (float*)d_out;

    const int* src = ei;            // edge_index[0]
    const int* dst = ei + NE;       // edge_index[1]

    char* ws = (char*)d_ws;
    float* dinv = (float*)ws;                                   // NN floats
    float* buf  = (float*)(ws + ((NN * 4 + 255) / 256) * 256);  // NN*D floats

    const int B = 256;
    // degree / dinv
    k_init_deg <<<(NN + B - 1) / B, B, 0, stream>>>(dinv);
    k_count_deg<<<(NE + B - 1) / B, B, 0, stream>>>(dst, dinv);
    k_dinv     <<<(NN + B - 1) / B, B, 0, stream>>>(dinv);

    const int gridF = (NN * D + B - 1) / B;     // feature-space grid
    const int gridE = (NE * 64) / B;            // edge-wave grid (exact: 250000)

    // hop 1: x -> buf
    k_prop_init <<<gridF, B, 0, stream>>>(x, dinv, buf);
    k_prop_edges<<<gridE, B, 0, stream>>>(x, src, dst, dinv, buf);
    // hop 2: buf -> out
    k_prop_init <<<gridF, B, 0, stream>>>(buf, dinv, out);
    k_prop_edges<<<gridE, B, 0, stream>>>(buf, src, dst, dinv, out);
    // hop 3: out -> buf
    k_prop_init <<<gridF, B, 0, stream>>>(out, dinv, buf);
    k_prop_edges<<<gridE, B, 0, stream>>>(out, src, dst, dinv, buf);

    // linear: buf -> out
    k_linear<<<NN / 4, B, 0, stream>>>(buf, W, b, out);
}

// Round 2
// 487.416 us; speedup vs baseline: 1.6508x; 1.6508x over previous
//
#include <hip/hip_runtime.h>

#define NN 100000
#define NE 1000000
#define D  64
#define NB_SCAN 391   // ceil(NN/256)

// ======================= CSR build =======================

__global__ void k_hist(const int* __restrict__ dst, int* __restrict__ cnt) {
    int e = blockIdx.x * blockDim.x + threadIdx.x;
    if (e < NE) atomicAdd(&cnt[dst[e]], 1);
}

__global__ void k_dinv_from_cnt(const int* __restrict__ cnt, float* __restrict__ dinv) {
    int n = blockIdx.x * blockDim.x + threadIdx.x;
    if (n < NN) dinv[n] = rsqrtf((float)(cnt[n] + 1));  // +1 self loop
}

// exclusive scan of cnt -> rowptr, 3-kernel: per-block scan + partials
__global__ void k_scan1(const int* __restrict__ cnt, int* __restrict__ rowptr,
                        int* __restrict__ partials) {
    __shared__ int s[256];
    int i = blockIdx.x * 256 + threadIdx.x;
    int v = (i < NN) ? cnt[i] : 0;
    s[threadIdx.x] = v;
    __syncthreads();
    for (int off = 1; off < 256; off <<= 1) {
        int t = (threadIdx.x >= off) ? s[threadIdx.x - off] : 0;
        __syncthreads();
        s[threadIdx.x] += t;
        __syncthreads();
    }
    if (i < NN) rowptr[i] = s[threadIdx.x] - v;          // exclusive within block
    if (threadIdx.x == 255) partials[blockIdx.x] = s[255];
}

__global__ void k_scan2(int* __restrict__ partials) {
    __shared__ int s[512];
    int tid = threadIdx.x;
    int v = (tid < NB_SCAN) ? partials[tid] : 0;
    s[tid] = v;
    __syncthreads();
    for (int off = 1; off < 512; off <<= 1) {
        int t = (tid >= off) ? s[tid - off] : 0;
        __syncthreads();
        s[tid] += t;
        __syncthreads();
    }
    if (tid < NB_SCAN) partials[tid] = s[tid] - v;       // exclusive prefix of partials
}

__global__ void k_scan3(int* __restrict__ rowptr, const int* __restrict__ partials,
                        int* __restrict__ pos) {
    int i = blockIdx.x * 256 + threadIdx.x;
    if (i < NN) {
        int r = rowptr[i] + partials[blockIdx.x];
        rowptr[i] = r;
        pos[i] = r;                                      // fill cursor copy
    }
    if (i == 0) rowptr[NN] = NE;                         // total is exact
}

__global__ void k_fill(const int* __restrict__ src, const int* __restrict__ dst,
                       int* __restrict__ pos, int* __restrict__ col) {
    int e = blockIdx.x * blockDim.x + threadIdx.x;
    if (e < NE) {
        int p = atomicAdd(&pos[dst[e]], 1);
        col[p] = src[e];
    }
}

// ======================= propagation (pull, no atomics) =======================
// out[n] = dinv[n] * ( dinv[n]*in[n] + sum_{s in N(n)} dinv[s]*in[s] )
__global__ __launch_bounds__(256) void k_gather(const float* __restrict__ in,
                                                const int* __restrict__ rowptr,
                                                const int* __restrict__ col,
                                                const float* __restrict__ dinv,
                                                float* __restrict__ out) {
    int t = blockIdx.x * 256 + threadIdx.x;
    int n = t >> 6, lane = t & 63;
    if (n >= NN) return;
    int beg = rowptr[n], end = rowptr[n + 1];
    float dn = dinv[n];
    float acc = dn * in[(size_t)n * D + lane];
    for (int i = beg; i < end; ++i) {
        int s = col[i];
        acc = fmaf(dinv[s], in[(size_t)s * D + lane], acc);
    }
    out[(size_t)n * D + lane] = dn * acc;
}

// hop 3 fused with linear: y[n,o] = b[o] + sum_i row[n,i] * W[o,i]
__global__ __launch_bounds__(256) void k_gather_linear(const float* __restrict__ in,
                                                       const int* __restrict__ rowptr,
                                                       const int* __restrict__ col,
                                                       const float* __restrict__ dinv,
                                                       const float* __restrict__ W,
                                                       const float* __restrict__ bias,
                                                       float* __restrict__ out) {
    __shared__ float Wt[64 * 65];   // Wt[i*65+o] = W[o*64+i], +1 pad: conflict-free
    __shared__ float rows[4][64];
    const int tid = threadIdx.x;
    for (int m = tid; m < 64 * 64; m += 256) {
        int o = m >> 6, i = m & 63;
        Wt[i * 65 + o] = W[m];
    }
    __syncthreads();

    int t = blockIdx.x * 256 + tid;
    int n = t >> 6, lane = t & 63, wave = tid >> 6;
    if (n >= NN) return;
    int beg = rowptr[n], end = rowptr[n + 1];
    float dn = dinv[n];
    float acc = dn * in[(size_t)n * D + lane];
    for (int i = beg; i < end; ++i) {
        int s = col[i];
        acc = fmaf(dinv[s], in[(size_t)s * D + lane], acc);
    }
    rows[wave][lane] = dn * acc;    // wave-internal exchange (lockstep, no barrier)
    float o = bias[lane];
    #pragma unroll
    for (int i = 0; i < 64; ++i)
        o = fmaf(rows[wave][i], Wt[i * 65 + lane], o);
    out[(size_t)n * D + lane] = o;
}

// ======================= fallback path (round-1, atomic scatter) =======================

__global__ void k_init_deg(float* __restrict__ deg) {
    int n = blockIdx.x * blockDim.x + threadIdx.x;
    if (n < NN) deg[n] = 1.0f;
}
__global__ void k_count_deg(const int* __restrict__ dst, float* __restrict__ deg) {
    int e = blockIdx.x * blockDim.x + threadIdx.x;
    if (e < NE) atomicAdd(&deg[dst[e]], 1.0f);
}
__global__ void k_dinv_f(float* __restrict__ deg) {
    int n = blockIdx.x * blockDim.x + threadIdx.x;
    if (n < NN) deg[n] = rsqrtf(deg[n]);
}
__global__ void k_prop_init(const float* __restrict__ in, const float* __restrict__ dinv,
                            float* __restrict__ out) {
    int i = blockIdx.x * blockDim.x + threadIdx.x;
    if (i < NN * D) {
        int n = i >> 6;
        float di = dinv[n];
        out[i] = di * di * in[i];
    }
}
__global__ __launch_bounds__(256) void k_prop_edges(const float* __restrict__ in,
                                                    const int* __restrict__ src,
                                                    const int* __restrict__ dst,
                                                    const float* __restrict__ dinv,
                                                    float* __restrict__ out) {
    int t = blockIdx.x * blockDim.x + threadIdx.x;
    int e = t >> 6, f = t & 63;
    if (e < NE) {
        int s = src[e], d = dst[e];
        float w = dinv[s] * dinv[d];
        atomicAdd(&out[d * D + f], w * in[s * D + f]);
    }
}
__global__ __launch_bounds__(256) void k_linear(const float* __restrict__ in,
                                                const float* __restrict__ W,
                                                const float* __restrict__ bias,
                                                float* __restrict__ out) {
    __shared__ float Wt[64 * 65];
    __shared__ float rows[4][64];
    const int tid = threadIdx.x;
    for (int m = tid; m < 64 * 64; m += 256) {
        int o = m >> 6, i = m & 63;
        Wt[i * 65 + o] = W[m];
    }
    __syncthreads();
    const int wave = tid >> 6, lane = tid & 63;
    const float bo = bias[lane];
    for (int base = blockIdx.x * 4; base < NN; base += gridDim.x * 4) {
        int n = base + wave;
        if (n < NN) {
            rows[wave][lane] = in[n * D + lane];
            float acc = bo;
            #pragma unroll
            for (int i = 0; i < 64; ++i)
                acc = fmaf(rows[wave][i], Wt[i * 65 + lane], acc);
            out[n * D + lane] = acc;
        }
    }
}

// ======================= launch =======================

extern "C" void kernel_launch(void* const* d_in, const int* in_sizes, int n_in,
                              void* d_out, int out_size, void* d_ws, size_t ws_size,
                              hipStream_t stream) {
    const float* x   = (const float*)d_in[0];
    const int*   ei  = (const int*)d_in[1];
    const float* W   = (const float*)d_in[2];
    const float* b   = (const float*)d_in[3];
    float* out = (float*)d_out;

    const int* src = ei;        // edge_index[0]
    const int* dst = ei + NE;   // edge_index[1]

    char* ws = (char*)d_ws;
    size_t off = 0;
    auto take = [&](size_t bytes) -> char* {
        char* p = ws + off;
        off = (off + bytes + 255) & ~(size_t)255;
        return p;
    };

    float* dinv   = (float*)take((size_t)NN * 4);
    float* buf    = (float*)take((size_t)NN * D * 4);
    int* cnt      = (int*)take((size_t)NN * 4);
    int* rowptr   = (int*)take((size_t)(NN + 1) * 4);
    int* pos      = (int*)take((size_t)NN * 4);
    int* col      = (int*)take((size_t)NE * 4);
    int* partials = (int*)take(512 * 4);
    const bool use_csr = (off <= ws_size);

    const int B = 256;
    const int gridE1 = (NE + B - 1) / B;   // 3907: one thread per edge
    const int gridN1 = (NN + B - 1) / B;   // 391:  one thread per node
    const int gridNW = (NN * D) / B;       // 25000: one wave per node

    if (use_csr) {
        hipMemsetAsync(cnt, 0, (size_t)NN * 4, stream);
        k_hist         <<<gridE1, B, 0, stream>>>(dst, cnt);
        k_dinv_from_cnt<<<gridN1, B, 0, stream>>>(cnt, dinv);
        k_scan1        <<<NB_SCAN, 256, 0, stream>>>(cnt, rowptr, partials);
        k_scan2        <<<1, 512, 0, stream>>>(partials);
        k_scan3        <<<NB_SCAN, 256, 0, stream>>>(rowptr, partials, pos);
        k_fill         <<<gridE1, B, 0, stream>>>(src, dst, pos, col);

        k_gather       <<<gridNW, B, 0, stream>>>(x,   rowptr, col, dinv, out);  // hop1: x   -> out
        k_gather       <<<gridNW, B, 0, stream>>>(out, rowptr, col, dinv, buf);  // hop2: out -> buf
        k_gather_linear<<<gridNW, B, 0, stream>>>(buf, rowptr, col, dinv, W, b, out); // hop3+lin
    } else {
        // fallback: round-1 atomic-scatter path (needs only dinv + buf)
        const int gridF = (NN * D + B - 1) / B;
        const int gridEW = (NE * 64) / B;
        k_init_deg <<<gridN1, B, 0, stream>>>(dinv);
        k_count_deg<<<gridE1, B, 0, stream>>>(dst, dinv);
        k_dinv_f   <<<gridN1, B, 0, stream>>>(dinv);
        k_prop_init <<<gridF, B, 0, stream>>>(x, dinv, buf);
        k_prop_edges<<<gridEW, B, 0, stream>>>(x, src, dst, dinv, buf);
        k_prop_init <<<gridF, B, 0, stream>>>(buf, dinv, out);
        k_prop_edges<<<gridEW, B, 0, stream>>>(buf, src, dst, dinv, out);
        k_prop_init <<<gridF, B, 0, stream>>>(out, dinv, buf);
        k_prop_edges<<<gridEW, B, 0, stream>>>(out, src, dst, dinv, buf);
        k_linear<<<NN / 4, B, 0, stream>>>(buf, W, b, out);
    }
}

// Round 3
// 359.971 us; speedup vs baseline: 2.2353x; 1.3540x over previous
//
#include <hip/hip_runtime.h>

#define NN 100000
#define NE 1000000
#define D  64
#define NB_SCAN 391    // ceil(NN/256)
#define NCHUNK 6250    // NN/16 nodes-per-block-chunk

// ======================= CSR build =======================

__global__ void k_hist(const int* __restrict__ dst, int* __restrict__ cnt) {
    int e = blockIdx.x * blockDim.x + threadIdx.x;
    if (e < NE) atomicAdd(&cnt[dst[e]], 1);
}

// per-block exclusive scan of cnt -> rowptr; also computes dinv = rsqrt(cnt+1)
__global__ void k_scan1(const int* __restrict__ cnt, int* __restrict__ rowptr,
                        int* __restrict__ partials, float* __restrict__ dinv) {
    __shared__ int s[256];
    int i = blockIdx.x * 256 + threadIdx.x;
    int v = (i < NN) ? cnt[i] : 0;
    if (i < NN) dinv[i] = rsqrtf((float)(v + 1));   // +1 self loop
    s[threadIdx.x] = v;
    __syncthreads();
    for (int off = 1; off < 256; off <<= 1) {
        int t = (threadIdx.x >= off) ? s[threadIdx.x - off] : 0;
        __syncthreads();
        s[threadIdx.x] += t;
        __syncthreads();
    }
    if (i < NN) rowptr[i] = s[threadIdx.x] - v;
    if (threadIdx.x == 255) partials[blockIdx.x] = s[255];
}

__global__ void k_scan2(int* __restrict__ partials) {
    __shared__ int s[512];
    int tid = threadIdx.x;
    int v = (tid < NB_SCAN) ? partials[tid] : 0;
    s[tid] = v;
    __syncthreads();
    for (int off = 1; off < 512; off <<= 1) {
        int t = (tid >= off) ? s[tid - off] : 0;
        __syncthreads();
        s[tid] += t;
        __syncthreads();
    }
    if (tid < NB_SCAN) partials[tid] = s[tid] - v;
}

__global__ void k_scan3(int* __restrict__ rowptr, const int* __restrict__ partials,
                        int* __restrict__ pos) {
    int i = blockIdx.x * 256 + threadIdx.x;
    if (i < NN) {
        int r = rowptr[i] + partials[blockIdx.x];
        rowptr[i] = r;
        pos[i] = r;
    }
    if (i == 0) rowptr[NN] = NE;
}

// edge pairs: cw[p] = {src, bits(dinv[src])} — one 8B load serves the hop inner loop
__global__ void k_fill(const int* __restrict__ src, const int* __restrict__ dst,
                       const float* __restrict__ dinv,
                       int* __restrict__ pos, int2* __restrict__ cw) {
    int e = blockIdx.x * blockDim.x + threadIdx.x;
    if (e < NE) {
        int s = src[e];
        int p = atomicAdd(&pos[dst[e]], 1);
        int2 pr;
        pr.x = s;
        pr.y = __float_as_int(dinv[s]);
        cw[p] = pr;
    }
}

// ======================= propagation (pull, 4 nodes/wave, float4) =======================
// out[n] = dinv[n] * ( dinv[n]*in[n] + sum_{s in N(n)} dinv[s]*in[s] )

__global__ __launch_bounds__(256) void k_gather4(const float4* __restrict__ in4,
                                                 const int* __restrict__ rowptr,
                                                 const int2* __restrict__ cw,
                                                 const float* __restrict__ dinv,
                                                 float4* __restrict__ out4) {
    const int tid = threadIdx.x;
    const int nic = tid >> 4;           // node-in-chunk 0..15
    const int l   = tid & 15;           // float4 slot within row
    const int n   = blockIdx.x * 16 + nic;   // 6250*16 == NN exactly

    const int beg = rowptr[n], end = rowptr[n + 1];
    const float dn = dinv[n];

    float4 a0 = in4[(size_t)n * 16 + l];
    a0.x *= dn; a0.y *= dn; a0.z *= dn; a0.w *= dn;
    float4 a1 = make_float4(0.f, 0.f, 0.f, 0.f);

    int i = beg;
    for (; i + 1 < end; i += 2) {
        int2 p0 = cw[i];
        int2 p1 = cw[i + 1];
        float w0 = __int_as_float(p0.y);
        float w1 = __int_as_float(p1.y);
        float4 r0 = in4[(size_t)p0.x * 16 + l];
        float4 r1 = in4[(size_t)p1.x * 16 + l];
        a0.x = fmaf(w0, r0.x, a0.x); a0.y = fmaf(w0, r0.y, a0.y);
        a0.z = fmaf(w0, r0.z, a0.z); a0.w = fmaf(w0, r0.w, a0.w);
        a1.x = fmaf(w1, r1.x, a1.x); a1.y = fmaf(w1, r1.y, a1.y);
        a1.z = fmaf(w1, r1.z, a1.z); a1.w = fmaf(w1, r1.w, a1.w);
    }
    if (i < end) {
        int2 p0 = cw[i];
        float w0 = __int_as_float(p0.y);
        float4 r0 = in4[(size_t)p0.x * 16 + l];
        a0.x = fmaf(w0, r0.x, a0.x); a0.y = fmaf(w0, r0.y, a0.y);
        a0.z = fmaf(w0, r0.z, a0.z); a0.w = fmaf(w0, r0.w, a0.w);
    }
    float4 r;
    r.x = dn * (a0.x + a1.x);
    r.y = dn * (a0.y + a1.y);
    r.z = dn * (a0.z + a1.z);
    r.w = dn * (a0.w + a1.w);
    out4[(size_t)n * 16 + l] = r;
}

// hop 3 fused with linear; W staged ONCE per block, block chunk-strides.
__global__ __launch_bounds__(256) void k_gather_linear4(const float4* __restrict__ in4,
                                                        const int* __restrict__ rowptr,
                                                        const int2* __restrict__ cw,
                                                        const float* __restrict__ dinv,
                                                        const float* __restrict__ W,
                                                        const float* __restrict__ bias,
                                                        float4* __restrict__ out4) {
    __shared__ float4 Wq[64 * 16];      // Wq[i*16+l] = {W[4l+0][i],W[4l+1][i],W[4l+2][i],W[4l+3][i]}
    __shared__ float rowbuf[16][68];    // 68: 16B-aligned rows + conflict-free broadcast

    const int tid = threadIdx.x;
    for (int m = tid; m < 64 * 16; m += 256) {
        int i = m >> 4, l = m & 15;
        float4 v;
        v.x = W[(4 * l + 0) * 64 + i];
        v.y = W[(4 * l + 1) * 64 + i];
        v.z = W[(4 * l + 2) * 64 + i];
        v.w = W[(4 * l + 3) * 64 + i];
        Wq[m] = v;
    }
    __syncthreads();

    const int nic = tid >> 4;
    const int l   = tid & 15;
    const float4 bv = *(const float4*)&bias[4 * l];

    for (int chunk = blockIdx.x; chunk < NCHUNK; chunk += gridDim.x) {
        const int n = chunk * 16 + nic;
        const int beg = rowptr[n], end = rowptr[n + 1];
        const float dn = dinv[n];

        float4 a0 = in4[(size_t)n * 16 + l];
        a0.x *= dn; a0.y *= dn; a0.z *= dn; a0.w *= dn;
        float4 a1 = make_float4(0.f, 0.f, 0.f, 0.f);

        int i = beg;
        for (; i + 1 < end; i += 2) {
            int2 p0 = cw[i];
            int2 p1 = cw[i + 1];
            float w0 = __int_as_float(p0.y);
            float w1 = __int_as_float(p1.y);
            float4 r0 = in4[(size_t)p0.x * 16 + l];
            float4 r1 = in4[(size_t)p1.x * 16 + l];
            a0.x = fmaf(w0, r0.x, a0.x); a0.y = fmaf(w0, r0.y, a0.y);
            a0.z = fmaf(w0, r0.z, a0.z); a0.w = fmaf(w0, r0.w, a0.w);
            a1.x = fmaf(w1, r1.x, a1.x); a1.y = fmaf(w1, r1.y, a1.y);
            a1.z = fmaf(w1, r1.z, a1.z); a1.w = fmaf(w1, r1.w, a1.w);
        }
        if (i < end) {
            int2 p0 = cw[i];
            float w0 = __int_as_float(p0.y);
            float4 r0 = in4[(size_t)p0.x * 16 + l];
            a0.x = fmaf(w0, r0.x, a0.x); a0.y = fmaf(w0, r0.y, a0.y);
            a0.z = fmaf(w0, r0.z, a0.z); a0.w = fmaf(w0, r0.w, a0.w);
        }
        float4 r;
        r.x = dn * (a0.x + a1.x);
        r.y = dn * (a0.y + a1.y);
        r.z = dn * (a0.z + a1.z);
        r.w = dn * (a0.w + a1.w);

        // row -> LDS (wave-internal: in-order DS ops, no barrier needed)
        *(float4*)&rowbuf[nic][4 * l] = r;

        float4 y = bv;
        #pragma unroll
        for (int k = 0; k < 64; ++k) {
            float ri = rowbuf[nic][k];
            float4 w = Wq[k * 16 + l];
            y.x = fmaf(ri, w.x, y.x);
            y.y = fmaf(ri, w.y, y.y);
            y.z = fmaf(ri, w.z, y.z);
            y.w = fmaf(ri, w.w, y.w);
        }
        out4[(size_t)n * 16 + l] = y;
    }
}

// ======================= fallback path (atomic scatter, round-1) =======================

__global__ void k_init_deg(float* __restrict__ deg) {
    int n = blockIdx.x * blockDim.x + threadIdx.x;
    if (n < NN) deg[n] = 1.0f;
}
__global__ void k_count_deg(const int* __restrict__ dst, float* __restrict__ deg) {
    int e = blockIdx.x * blockDim.x + threadIdx.x;
    if (e < NE) atomicAdd(&deg[dst[e]], 1.0f);
}
__global__ void k_dinv_f(float* __restrict__ deg) {
    int n = blockIdx.x * blockDim.x + threadIdx.x;
    if (n < NN) deg[n] = rsqrtf(deg[n]);
}
__global__ void k_prop_init(const float* __restrict__ in, const float* __restrict__ dinv,
                            float* __restrict__ out) {
    int i = blockIdx.x * blockDim.x + threadIdx.x;
    if (i < NN * D) {
        int n = i >> 6;
        float di = dinv[n];
        out[i] = di * di * in[i];
    }
}
__global__ __launch_bounds__(256) void k_prop_edges(const float* __restrict__ in,
                                                    const int* __restrict__ src,
                                                    const int* __restrict__ dst,
                                                    const float* __restrict__ dinv,
                                                    float* __restrict__ out) {
    int t = blockIdx.x * blockDim.x + threadIdx.x;
    int e = t >> 6, f = t & 63;
    if (e < NE) {
        int s = src[e], d = dst[e];
        float w = dinv[s] * dinv[d];
        atomicAdd(&out[d * D + f], w * in[s * D + f]);
    }
}
__global__ __launch_bounds__(256) void k_linear(const float* __restrict__ in,
                                                const float* __restrict__ W,
                                                const float* __restrict__ bias,
                                                float* __restrict__ out) {
    __shared__ float Wt[64 * 65];
    __shared__ float rows[4][64];
    const int tid = threadIdx.x;
    for (int m = tid; m < 64 * 64; m += 256) {
        int o = m >> 6, i = m & 63;
        Wt[i * 65 + o] = W[m];
    }
    __syncthreads();
    const int wave = tid >> 6, lane = tid & 63;
    const float bo = bias[lane];
    for (int base = blockIdx.x * 4; base < NN; base += gridDim.x * 4) {
        int n = base + wave;
        if (n < NN) {
            rows[wave][lane] = in[n * D + lane];
            float acc = bo;
            #pragma unroll
            for (int i = 0; i < 64; ++i)
                acc = fmaf(rows[wave][i], Wt[i * 65 + lane], acc);
            out[n * D + lane] = acc;
        }
    }
}

// ======================= launch =======================

extern "C" void kernel_launch(void* const* d_in, const int* in_sizes, int n_in,
                              void* d_out, int out_size, void* d_ws, size_t ws_size,
                              hipStream_t stream) {
    const float* x   = (const float*)d_in[0];
    const int*   ei  = (const int*)d_in[1];
    const float* W   = (const float*)d_in[2];
    const float* b   = (const float*)d_in[3];
    float* out = (float*)d_out;

    const int* src = ei;        // edge_index[0]
    const int* dst = ei + NE;   // edge_index[1]

    char* ws = (char*)d_ws;
    size_t off = 0;
    auto take = [&](size_t bytes) -> char* {
        char* p = ws + off;
        off = (off + bytes + 255) & ~(size_t)255;
        return p;
    };

    float* dinv   = (float*)take((size_t)NN * 4);
    float* buf    = (float*)take((size_t)NN * D * 4);
    int* cnt      = (int*)take((size_t)NN * 4);
    int* rowptr   = (int*)take((size_t)(NN + 1) * 4);
    int* pos      = (int*)take((size_t)NN * 4);
    int2* cw      = (int2*)take((size_t)NE * 8);
    int* partials = (int*)take(512 * 4);
    const bool use_csr = (off <= ws_size);

    const int B = 256;
    const int gridE1 = (NE + B - 1) / B;
    const int gridN1 = (NN + B - 1) / B;

    if (use_csr) {
        hipMemsetAsync(cnt, 0, (size_t)NN * 4, stream);
        k_hist <<<gridE1, B, 0, stream>>>(dst, cnt);
        k_scan1<<<NB_SCAN, 256, 0, stream>>>(cnt, rowptr, partials, dinv);
        k_scan2<<<1, 512, 0, stream>>>(partials);
        k_scan3<<<NB_SCAN, 256, 0, stream>>>(rowptr, partials, pos);
        k_fill <<<gridE1, B, 0, stream>>>(src, dst, dinv, pos, cw);

        const float4* x4   = (const float4*)x;
        float4*       out4 = (float4*)out;
        float4*       buf4 = (float4*)buf;
        k_gather4<<<NCHUNK, B, 0, stream>>>(x4, rowptr, cw, dinv, out4);              // hop1: x   -> out
        k_gather4<<<NCHUNK, B, 0, stream>>>((const float4*)out4, rowptr, cw, dinv, buf4); // hop2: out -> buf
        k_gather_linear4<<<2048, B, 0, stream>>>((const float4*)buf4, rowptr, cw, dinv,
                                                 W, b, out4);                          // hop3 + linear
    } else {
        const int gridF = (NN * D + B - 1) / B;
        const int gridEW = (NE * 64) / B;
        k_init_deg <<<gridN1, B, 0, stream>>>(dinv);
        k_count_deg<<<gridE1, B, 0, stream>>>(dst, dinv);
        k_dinv_f   <<<gridN1, B, 0, stream>>>(dinv);
        k_prop_init <<<gridF, B, 0, stream>>>(x, dinv, buf);
        k_prop_edges<<<gridEW, B, 0, stream>>>(x, src, dst, dinv, buf);
        k_prop_init <<<gridF, B, 0, stream>>>(buf, dinv, out);
        k_prop_edges<<<gridEW, B, 0, stream>>>(buf, src, dst, dinv, out);
        k_prop_init <<<gridF, B, 0, stream>>>(out, dinv, buf);
        k_prop_edges<<<gridEW, B, 0, stream>>>(out, src, dst, dinv, buf);
        k_linear<<<NN / 4, B, 0, stream>>>(buf, W, b, out);
    }
}

// Round 4
// 282.696 us; speedup vs baseline: 2.8463x; 1.2734x over previous
//
#include <hip/hip_runtime.h>

#define NN 100000
#define NE 1000000
#define D  64
#define NB_SCAN 391    // ceil(NN/256)
#define NCH_GATHER 6250  // NN/16
#define NCH_LIN 1563     // ceil(NN/64)

// ======================= CSR build =======================

__global__ void k_hist(const int* __restrict__ dst, int* __restrict__ cnt) {
    int e = blockIdx.x * blockDim.x + threadIdx.x;
    if (e < NE) atomicAdd(&cnt[dst[e]], 1);
}

// per-block exclusive scan of cnt -> rowptr; also computes dinv = rsqrt(cnt+1)
__global__ void k_scan1(const int* __restrict__ cnt, int* __restrict__ rowptr,
                        int* __restrict__ partials, float* __restrict__ dinv) {
    __shared__ int s[256];
    int i = blockIdx.x * 256 + threadIdx.x;
    int v = (i < NN) ? cnt[i] : 0;
    if (i < NN) dinv[i] = rsqrtf((float)(v + 1));   // +1 self loop
    s[threadIdx.x] = v;
    __syncthreads();
    for (int off = 1; off < 256; off <<= 1) {
        int t = (threadIdx.x >= off) ? s[threadIdx.x - off] : 0;
        __syncthreads();
        s[threadIdx.x] += t;
        __syncthreads();
    }
    if (i < NN) rowptr[i] = s[threadIdx.x] - v;
    if (threadIdx.x == 255) partials[blockIdx.x] = s[255];
}

__global__ void k_scan2(int* __restrict__ partials) {
    __shared__ int s[512];
    int tid = threadIdx.x;
    int v = (tid < NB_SCAN) ? partials[tid] : 0;
    s[tid] = v;
    __syncthreads();
    for (int off = 1; off < 512; off <<= 1) {
        int t = (tid >= off) ? s[tid - off] : 0;
        __syncthreads();
        s[tid] += t;
        __syncthreads();
    }
    if (tid < NB_SCAN) partials[tid] = s[tid] - v;
}

__global__ void k_scan3(int* __restrict__ rowptr, const int* __restrict__ partials,
                        int* __restrict__ pos) {
    int i = blockIdx.x * 256 + threadIdx.x;
    if (i < NN) {
        int r = rowptr[i] + partials[blockIdx.x];
        rowptr[i] = r;
        pos[i] = r;
    }
    if (i == 0) rowptr[NN] = NE;
}

// edge pairs: cw[p] = {src, bits(dinv[src])}
__global__ void k_fill(const int* __restrict__ src, const int* __restrict__ dst,
                       const float* __restrict__ dinv,
                       int* __restrict__ pos, int2* __restrict__ cw) {
    int e = blockIdx.x * blockDim.x + threadIdx.x;
    if (e < NE) {
        int s = src[e];
        int p = atomicAdd(&pos[dst[e]], 1);
        int2 pr;
        pr.x = s;
        pr.y = __float_as_int(dinv[s]);
        cw[p] = pr;
    }
}

// ======================= propagation (pull, 4 nodes/wave, float4) =======================
// out[n] = dinv[n] * ( dinv[n]*in[n] + sum_{s in N(n)} dinv[s]*in[s] )
// Edge list for the node preloaded into the group's 16 lanes; inner loop gets
// src/weight via __shfl (VALU) instead of a dependent load. 4-deep unroll.

__global__ __launch_bounds__(256) void k_gather4(const float4* __restrict__ in4,
                                                 const int* __restrict__ rowptr,
                                                 const int2* __restrict__ cw,
                                                 const float* __restrict__ dinv,
                                                 float4* __restrict__ out4) {
    const int tid = threadIdx.x;
    const int l = tid & 15;
    const int n = blockIdx.x * 16 + (tid >> 4);   // 6250*16 == NN exactly

    const int beg = rowptr[n], end = rowptr[n + 1];
    const int deg = end - beg;
    const float dn = dinv[n];

    float4 a0 = in4[(size_t)n * 16 + l];
    a0.x *= dn; a0.y *= dn; a0.z *= dn; a0.w *= dn;
    float4 a1 = make_float4(0.f, 0.f, 0.f, 0.f);
    float4 a2 = make_float4(0.f, 0.f, 0.f, 0.f);
    float4 a3 = make_float4(0.f, 0.f, 0.f, 0.f);

    if (deg > 0) {
        int2 cwv = cw[beg + (l < deg ? l : deg - 1)];   // lanewise preload of ≤16 edges
        const int kmax = deg < 16 ? deg : 16;
        int k = 0;
        for (; k + 3 < kmax; k += 4) {
            int   s0 = __shfl(cwv.x, k + 0, 16);
            int   s1 = __shfl(cwv.x, k + 1, 16);
            int   s2 = __shfl(cwv.x, k + 2, 16);
            int   s3 = __shfl(cwv.x, k + 3, 16);
            float w0 = __int_as_float(__shfl(cwv.y, k + 0, 16));
            float w1 = __int_as_float(__shfl(cwv.y, k + 1, 16));
            float w2 = __int_as_float(__shfl(cwv.y, k + 2, 16));
            float w3 = __int_as_float(__shfl(cwv.y, k + 3, 16));
            float4 r0 = in4[(size_t)s0 * 16 + l];
            float4 r1 = in4[(size_t)s1 * 16 + l];
            float4 r2 = in4[(size_t)s2 * 16 + l];
            float4 r3 = in4[(size_t)s3 * 16 + l];
            a0.x = fmaf(w0, r0.x, a0.x); a0.y = fmaf(w0, r0.y, a0.y);
            a0.z = fmaf(w0, r0.z, a0.z); a0.w = fmaf(w0, r0.w, a0.w);
            a1.x = fmaf(w1, r1.x, a1.x); a1.y = fmaf(w1, r1.y, a1.y);
            a1.z = fmaf(w1, r1.z, a1.z); a1.w = fmaf(w1, r1.w, a1.w);
            a2.x = fmaf(w2, r2.x, a2.x); a2.y = fmaf(w2, r2.y, a2.y);
            a2.z = fmaf(w2, r2.z, a2.z); a2.w = fmaf(w2, r2.w, a2.w);
            a3.x = fmaf(w3, r3.x, a3.x); a3.y = fmaf(w3, r3.y, a3.y);
            a3.z = fmaf(w3, r3.z, a3.z); a3.w = fmaf(w3, r3.w, a3.w);
        }
        for (; k < kmax; ++k) {
            int   s0 = __shfl(cwv.x, k, 16);
            float w0 = __int_as_float(__shfl(cwv.y, k, 16));
            float4 r0 = in4[(size_t)s0 * 16 + l];
            a0.x = fmaf(w0, r0.x, a0.x); a0.y = fmaf(w0, r0.y, a0.y);
            a0.z = fmaf(w0, r0.z, a0.z); a0.w = fmaf(w0, r0.w, a0.w);
        }
        // rare tail: deg > 16 (P ≈ 3% for Poisson(10))
        for (int i = beg + 16; i + 1 < end; i += 2) {
            int2 p0 = cw[i];
            int2 p1 = cw[i + 1];
            float w0 = __int_as_float(p0.y);
            float w1 = __int_as_float(p1.y);
            float4 r0 = in4[(size_t)p0.x * 16 + l];
            float4 r1 = in4[(size_t)p1.x * 16 + l];
            a1.x = fmaf(w0, r0.x, a1.x); a1.y = fmaf(w0, r0.y, a1.y);
            a1.z = fmaf(w0, r0.z, a1.z); a1.w = fmaf(w0, r0.w, a1.w);
            a2.x = fmaf(w1, r1.x, a2.x); a2.y = fmaf(w1, r1.y, a2.y);
            a2.z = fmaf(w1, r1.z, a2.z); a2.w = fmaf(w1, r1.w, a2.w);
        }
        if (deg > 16 && ((deg - 16) & 1)) {
            int2 p0 = cw[end - 1];
            float w0 = __int_as_float(p0.y);
            float4 r0 = in4[(size_t)p0.x * 16 + l];
            a3.x = fmaf(w0, r0.x, a3.x); a3.y = fmaf(w0, r0.y, a3.y);
            a3.z = fmaf(w0, r0.z, a3.z); a3.w = fmaf(w0, r0.w, a3.w);
        }
    }
    float4 r;
    r.x = dn * ((a0.x + a1.x) + (a2.x + a3.x));
    r.y = dn * ((a0.y + a1.y) + (a2.y + a3.y));
    r.z = dn * ((a0.z + a1.z) + (a2.z + a3.z));
    r.w = dn * ((a0.w + a1.w) + (a2.w + a3.w));
    out4[(size_t)n * 16 + l] = r;
}

// ======================= linear (in-place safe: row-local) =======================
// 16-lane group handles 4 nodes: each 16B Wq LDS read amortized over 4 rows.
__global__ __launch_bounds__(256) void k_linear4(const float4* in4,
                                                 const float* __restrict__ W,
                                                 const float* __restrict__ bias,
                                                 float4* out4) {
    __shared__ float4 Wq[64 * 16];     // Wq[i*16+l] = {W[4l+c][i], c=0..3}
    __shared__ float rowbuf[64][68];   // [node-in-chunk][feature], padded

    const int tid = threadIdx.x;
    for (int m = tid; m < 64 * 16; m += 256) {
        int i = m >> 4, l = m & 15;
        float4 v;
        v.x = W[(4 * l + 0) * 64 + i];
        v.y = W[(4 * l + 1) * 64 + i];
        v.z = W[(4 * l + 2) * 64 + i];
        v.w = W[(4 * l + 3) * 64 + i];
        Wq[m] = v;
    }
    __syncthreads();

    const int g = tid >> 4;    // group 0..15 -> nodes 4g..4g+3 of the chunk
    const int l = tid & 15;
    const float4 bv = *(const float4*)&bias[4 * l];

    for (int chunk = blockIdx.x; chunk < NCH_LIN; chunk += gridDim.x) {
        const int nb = chunk * 64 + 4 * g;
        const int n0 = nb, n1 = nb + 1, n2 = nb + 2, n3 = nb + 3;
        // read rows fully before any write of them (in-place safe, group-local)
        float4 r0 = in4[(size_t)(n0 < NN ? n0 : NN - 1) * 16 + l];
        float4 r1 = in4[(size_t)(n1 < NN ? n1 : NN - 1) * 16 + l];
        float4 r2 = in4[(size_t)(n2 < NN ? n2 : NN - 1) * 16 + l];
        float4 r3 = in4[(size_t)(n3 < NN ? n3 : NN - 1) * 16 + l];
        *(float4*)&rowbuf[4 * g + 0][4 * l] = r0;
        *(float4*)&rowbuf[4 * g + 1][4 * l] = r1;
        *(float4*)&rowbuf[4 * g + 2][4 * l] = r2;
        *(float4*)&rowbuf[4 * g + 3][4 * l] = r3;
        // group-local rows: wave-lockstep DS ordering, no barrier needed

        float4 y0 = bv, y1 = bv, y2 = bv, y3 = bv;
        #pragma unroll
        for (int kq = 0; kq < 16; ++kq) {
            float4 ri0 = *(const float4*)&rowbuf[4 * g + 0][4 * kq];
            float4 ri1 = *(const float4*)&rowbuf[4 * g + 1][4 * kq];
            float4 ri2 = *(const float4*)&rowbuf[4 * g + 2][4 * kq];
            float4 ri3 = *(const float4*)&rowbuf[4 * g + 3][4 * kq];
            float4 wq0 = Wq[(4 * kq + 0) * 16 + l];
            float4 wq1 = Wq[(4 * kq + 1) * 16 + l];
            float4 wq2 = Wq[(4 * kq + 2) * 16 + l];
            float4 wq3 = Wq[(4 * kq + 3) * 16 + l];
            y0.x = fmaf(ri0.x, wq0.x, y0.x); y0.y = fmaf(ri0.x, wq0.y, y0.y);
            y0.z = fmaf(ri0.x, wq0.z, y0.z); y0.w = fmaf(ri0.x, wq0.w, y0.w);
            y0.x = fmaf(ri0.y, wq1.x, y0.x); y0.y = fmaf(ri0.y, wq1.y, y0.y);
            y0.z = fmaf(ri0.y, wq1.z, y0.z); y0.w = fmaf(ri0.y, wq1.w, y0.w);
            y0.x = fmaf(ri0.z, wq2.x, y0.x); y0.y = fmaf(ri0.z, wq2.y, y0.y);
            y0.z = fmaf(ri0.z, wq2.z, y0.z); y0.w = fmaf(ri0.z, wq2.w, y0.w);
            y0.x = fmaf(ri0.w, wq3.x, y0.x); y0.y = fmaf(ri0.w, wq3.y, y0.y);
            y0.z = fmaf(ri0.w, wq3.z, y0.z); y0.w = fmaf(ri0.w, wq3.w, y0.w);

            y1.x = fmaf(ri1.x, wq0.x, y1.x); y1.y = fmaf(ri1.x, wq0.y, y1.y);
            y1.z = fmaf(ri1.x, wq0.z, y1.z); y1.w = fmaf(ri1.x, wq0.w, y1.w);
            y1.x = fmaf(ri1.y, wq1.x, y1.x); y1.y = fmaf(ri1.y, wq1.y, y1.y);
            y1.z = fmaf(ri1.y, wq1.z, y1.z); y1.w = fmaf(ri1.y, wq1.w, y1.w);
            y1.x = fmaf(ri1.z, wq2.x, y1.x); y1.y = fmaf(ri1.z, wq2.y, y1.y);
            y1.z = fmaf(ri1.z, wq2.z, y1.z); y1.w = fmaf(ri1.z, wq2.w, y1.w);
            y1.x = fmaf(ri1.w, wq3.x, y1.x); y1.y = fmaf(ri1.w, wq3.y, y1.y);
            y1.z = fmaf(ri1.w, wq3.z, y1.z); y1.w = fmaf(ri1.w, wq3.w, y1.w);

            y2.x = fmaf(ri2.x, wq0.x, y2.x); y2.y = fmaf(ri2.x, wq0.y, y2.y);
            y2.z = fmaf(ri2.x, wq0.z, y2.z); y2.w = fmaf(ri2.x, wq0.w, y2.w);
            y2.x = fmaf(ri2.y, wq1.x, y2.x); y2.y = fmaf(ri2.y, wq1.y, y2.y);
            y2.z = fmaf(ri2.y, wq1.z, y2.z); y2.w = fmaf(ri2.y, wq1.w, y2.w);
            y2.x = fmaf(ri2.z, wq2.x, y2.x); y2.y = fmaf(ri2.z, wq2.y, y2.y);
            y2.z = fmaf(ri2.z, wq2.z, y2.z); y2.w = fmaf(ri2.z, wq2.w, y2.w);
            y2.x = fmaf(ri2.w, wq3.x, y2.x); y2.y = fmaf(ri2.w, wq3.y, y2.y);
            y2.z = fmaf(ri2.w, wq3.z, y2.z); y2.w = fmaf(ri2.w, wq3.w, y2.w);

            y3.x = fmaf(ri3.x, wq0.x, y3.x); y3.y = fmaf(ri3.x, wq0.y, y3.y);
            y3.z = fmaf(ri3.x, wq0.z, y3.z); y3.w = fmaf(ri3.x, wq0.w, y3.w);
            y3.x = fmaf(ri3.y, wq1.x, y3.x); y3.y = fmaf(ri3.y, wq1.y, y3.y);
            y3.z = fmaf(ri3.y, wq1.z, y3.z); y3.w = fmaf(ri3.y, wq1.w, y3.w);
            y3.x = fmaf(ri3.z, wq2.x, y3.x); y3.y = fmaf(ri3.z, wq2.y, y3.y);
            y3.z = fmaf(ri3.z, wq2.z, y3.z); y3.w = fmaf(ri3.z, wq2.w, y3.w);
            y3.x = fmaf(ri3.w, wq3.x, y3.x); y3.y = fmaf(ri3.w, wq3.y, y3.y);
            y3.z = fmaf(ri3.w, wq3.z, y3.z); y3.w = fmaf(ri3.w, wq3.w, y3.w);
        }
        if (n0 < NN) out4[(size_t)n0 * 16 + l] = y0;
        if (n1 < NN) out4[(size_t)n1 * 16 + l] = y1;
        if (n2 < NN) out4[(size_t)n2 * 16 + l] = y2;
        if (n3 < NN) out4[(size_t)n3 * 16 + l] = y3;
    }
}

// ======================= fallback path (atomic scatter, round-1) =======================

__global__ void k_init_deg(float* __restrict__ deg) {
    int n = blockIdx.x * blockDim.x + threadIdx.x;
    if (n < NN) deg[n] = 1.0f;
}
__global__ void k_count_deg(const int* __restrict__ dst, float* __restrict__ deg) {
    int e = blockIdx.x * blockDim.x + threadIdx.x;
    if (e < NE) atomicAdd(&deg[dst[e]], 1.0f);
}
__global__ void k_dinv_f(float* __restrict__ deg) {
    int n = blockIdx.x * blockDim.x + threadIdx.x;
    if (n < NN) deg[n] = rsqrtf(deg[n]);
}
__global__ void k_prop_init(const float* __restrict__ in, const float* __restrict__ dinv,
                            float* __restrict__ out) {
    int i = blockIdx.x * blockDim.x + threadIdx.x;
    if (i < NN * D) {
        int n = i >> 6;
        float di = dinv[n];
        out[i] = di * di * in[i];
    }
}
__global__ __launch_bounds__(256) void k_prop_edges(const float* __restrict__ in,
                                                    const int* __restrict__ src,
                                                    const int* __restrict__ dst,
                                                    const float* __restrict__ dinv,
                                                    float* __restrict__ out) {
    int t = blockIdx.x * blockDim.x + threadIdx.x;
    int e = t >> 6, f = t & 63;
    if (e < NE) {
        int s = src[e], d = dst[e];
        float w = dinv[s] * dinv[d];
        atomicAdd(&out[d * D + f], w * in[s * D + f]);
    }
}
__global__ __launch_bounds__(256) void k_linear(const float* __restrict__ in,
                                                const float* __restrict__ W,
                                                const float* __restrict__ bias,
                                                float* __restrict__ out) {
    __shared__ float Wt[64 * 65];
    __shared__ float rows[4][64];
    const int tid = threadIdx.x;
    for (int m = tid; m < 64 * 64; m += 256) {
        int o = m >> 6, i = m & 63;
        Wt[i * 65 + o] = W[m];
    }
    __syncthreads();
    const int wave = tid >> 6, lane = tid & 63;
    const float bo = bias[lane];
    for (int base = blockIdx.x * 4; base < NN; base += gridDim.x * 4) {
        int n = base + wave;
        if (n < NN) {
            rows[wave][lane] = in[n * D + lane];
            float acc = bo;
            #pragma unroll
            for (int i = 0; i < 64; ++i)
                acc = fmaf(rows[wave][i], Wt[i * 65 + lane], acc);
            out[n * D + lane] = acc;
        }
    }
}

// ======================= launch =======================

extern "C" void kernel_launch(void* const* d_in, const int* in_sizes, int n_in,
                              void* d_out, int out_size, void* d_ws, size_t ws_size,
                              hipStream_t stream) {
    const float* x   = (const float*)d_in[0];
    const int*   ei  = (const int*)d_in[1];
    const float* W   = (const float*)d_in[2];
    const float* b   = (const float*)d_in[3];
    float* out = (float*)d_out;

    const int* src = ei;        // edge_index[0]
    const int* dst = ei + NE;   // edge_index[1]

    char* ws = (char*)d_ws;
    size_t off = 0;
    auto take = [&](size_t bytes) -> char* {
        char* p = ws + off;
        off = (off + bytes + 255) & ~(size_t)255;
        return p;
    };

    float* dinv   = (float*)take((size_t)NN * 4);
    float* buf    = (float*)take((size_t)NN * D * 4);
    int* cnt      = (int*)take((size_t)NN * 4);
    int* rowptr   = (int*)take((size_t)(NN + 1) * 4);
    int* pos      = (int*)take((size_t)NN * 4);
    int2* cw      = (int2*)take((size_t)NE * 8);
    int* partials = (int*)take(512 * 4);
    const bool use_csr = (off <= ws_size);

    const int B = 256;
    const int gridE1 = (NE + B - 1) / B;
    const int gridN1 = (NN + B - 1) / B;

    if (use_csr) {
        hipMemsetAsync(cnt, 0, (size_t)NN * 4, stream);
        k_hist <<<gridE1, B, 0, stream>>>(dst, cnt);
        k_scan1<<<NB_SCAN, 256, 0, stream>>>(cnt, rowptr, partials, dinv);
        k_scan2<<<1, 512, 0, stream>>>(partials);
        k_scan3<<<NB_SCAN, 256, 0, stream>>>(rowptr, partials, pos);
        k_fill <<<gridE1, B, 0, stream>>>(src, dst, dinv, pos, cw);

        const float4* x4   = (const float4*)x;
        float4*       out4 = (float4*)out;
        float4*       buf4 = (float4*)buf;
        k_gather4<<<NCH_GATHER, B, 0, stream>>>(x4, rowptr, cw, dinv, out4);                  // hop1: x   -> out
        k_gather4<<<NCH_GATHER, B, 0, stream>>>((const float4*)out4, rowptr, cw, dinv, buf4); // hop2: out -> buf
        k_gather4<<<NCH_GATHER, B, 0, stream>>>((const float4*)buf4, rowptr, cw, dinv, out4); // hop3: buf -> out
        k_linear4<<<1024, B, 0, stream>>>((const float4*)out4, W, b, out4);                   // linear in-place
    } else {
        const int gridF = (NN * D + B - 1) / B;
        const int gridEW = (NE * 64) / B;
        k_init_deg <<<gridN1, B, 0, stream>>>(dinv);
        k_count_deg<<<gridE1, B, 0, stream>>>(dst, dinv);
        k_dinv_f   <<<gridN1, B, 0, stream>>>(dinv);
        k_prop_init <<<gridF, B, 0, stream>>>(x, dinv, buf);
        k_prop_edges<<<gridEW, B, 0, stream>>>(x, src, dst, dinv, buf);
        k_prop_init <<<gridF, B, 0, stream>>>(buf, dinv, out);
        k_prop_edges<<<gridEW, B, 0, stream>>>(buf, src, dst, dinv, out);
        k_prop_init <<<gridF, B, 0, stream>>>(out, dinv, buf);
        k_prop_edges<<<gridEW, B, 0, stream>>>(out, src, dst, dinv, buf);
        k_linear<<<NN / 4, B, 0, stream>>>(buf, W, b, out);
    }
}

// Round 5
// 257.343 us; speedup vs baseline: 3.1267x; 1.0985x over previous
//
#include <hip/hip_runtime.h>

#define NN 100000
#define NE 1000000
#define D  64
#define CAP 32          // bucket capacity per node; Poisson(10) ⇒ P(deg>32) ≈ 1e-9/node
#define OVF_CAP 16384
#define NCH_LIN 1563    // ceil(NN/64)

// ======================= bucket build (one atomic pass, no scans) =======================

__global__ void k_fill_bucket(const int* __restrict__ src, const int* __restrict__ dst,
                              int* __restrict__ cnt, int* __restrict__ bucket,
                              int* __restrict__ ovf_n, int2* __restrict__ ovf) {
    int e = blockIdx.x * blockDim.x + threadIdx.x;
    if (e < NE) {
        int s = src[e], d = dst[e];
        int c = atomicAdd(&cnt[d], 1);
        if (c < CAP) {
            bucket[d * CAP + c] = s;
        } else {
            int i = atomicAdd(ovf_n, 1);
            if (i < OVF_CAP) ovf[i] = make_int2(s, d);
        }
    }
}

__global__ void k_dinv(const int* __restrict__ cnt, float* __restrict__ dinv) {
    int n = blockIdx.x * blockDim.x + threadIdx.x;
    if (n < NN) dinv[n] = rsqrtf((float)(cnt[n] + 1));   // +1 self loop
}

// ======================= propagation (pull, 4 nodes/wave, float4) =======================
// out[n] = dinv[n] * ( dinv[n]*in[n] + sum_{s in N(n)} dinv[s]*in[s] )
// Up to 32 edges preloaded into 2 regs per lane (parallel dinv gather at preload);
// inner loop gets src/weight via __shfl (VALU). 4-deep unroll, 4 accumulators.

__global__ __launch_bounds__(256) void k_gather32(const float4* __restrict__ in4,
                                                  const int* __restrict__ cnt,
                                                  const int* __restrict__ bucket,
                                                  const float* __restrict__ dinv,
                                                  float4* __restrict__ out4) {
    const int tid = threadIdx.x;
    const int l = tid & 15;
    const int n = blockIdx.x * 16 + (tid >> 4);   // 6250*16 == NN exactly

    const int deg = min(cnt[n], CAP);
    const float dn = dinv[n];

    float4 a0 = in4[(size_t)n * 16 + l];
    a0.x *= dn; a0.y *= dn; a0.z *= dn; a0.w *= dn;
    float4 a1 = make_float4(0.f, 0.f, 0.f, 0.f);
    float4 a2 = make_float4(0.f, 0.f, 0.f, 0.f);
    float4 a3 = make_float4(0.f, 0.f, 0.f, 0.f);

    if (deg > 0) {
        // lanewise preload of first 16 edges + their weights (parallel scattered loads)
        int   iA = (l < deg) ? l : 0;
        int   sA = bucket[n * CAP + iA];
        float wA = dinv[sA];
        const int kmax = deg < 16 ? deg : 16;
        int k = 0;
        for (; k + 3 < kmax; k += 4) {
            int   s0 = __shfl(sA, k + 0, 16);
            int   s1 = __shfl(sA, k + 1, 16);
            int   s2 = __shfl(sA, k + 2, 16);
            int   s3 = __shfl(sA, k + 3, 16);
            float w0 = __shfl(wA, k + 0, 16);
            float w1 = __shfl(wA, k + 1, 16);
            float w2 = __shfl(wA, k + 2, 16);
            float w3 = __shfl(wA, k + 3, 16);
            float4 r0 = in4[(size_t)s0 * 16 + l];
            float4 r1 = in4[(size_t)s1 * 16 + l];
            float4 r2 = in4[(size_t)s2 * 16 + l];
            float4 r3 = in4[(size_t)s3 * 16 + l];
            a0.x = fmaf(w0, r0.x, a0.x); a0.y = fmaf(w0, r0.y, a0.y);
            a0.z = fmaf(w0, r0.z, a0.z); a0.w = fmaf(w0, r0.w, a0.w);
            a1.x = fmaf(w1, r1.x, a1.x); a1.y = fmaf(w1, r1.y, a1.y);
            a1.z = fmaf(w1, r1.z, a1.z); a1.w = fmaf(w1, r1.w, a1.w);
            a2.x = fmaf(w2, r2.x, a2.x); a2.y = fmaf(w2, r2.y, a2.y);
            a2.z = fmaf(w2, r2.z, a2.z); a2.w = fmaf(w2, r2.w, a2.w);
            a3.x = fmaf(w3, r3.x, a3.x); a3.y = fmaf(w3, r3.y, a3.y);
            a3.z = fmaf(w3, r3.z, a3.z); a3.w = fmaf(w3, r3.w, a3.w);
        }
        for (; k < kmax; ++k) {
            int   s0 = __shfl(sA, k, 16);
            float w0 = __shfl(wA, k, 16);
            float4 r0 = in4[(size_t)s0 * 16 + l];
            a0.x = fmaf(w0, r0.x, a0.x); a0.y = fmaf(w0, r0.y, a0.y);
            a0.z = fmaf(w0, r0.z, a0.z); a0.w = fmaf(w0, r0.w, a0.w);
        }
        if (deg > 16) {   // P ≈ 3% of nodes
            int   iB = (16 + l < deg) ? (16 + l) : 0;
            int   sB = bucket[n * CAP + iB];
            float wB = dinv[sB];
            const int k2max = deg - 16;
            int k2 = 0;
            for (; k2 + 1 < k2max; k2 += 2) {
                int   s0 = __shfl(sB, k2 + 0, 16);
                int   s1 = __shfl(sB, k2 + 1, 16);
                float w0 = __shfl(wB, k2 + 0, 16);
                float w1 = __shfl(wB, k2 + 1, 16);
                float4 r0 = in4[(size_t)s0 * 16 + l];
                float4 r1 = in4[(size_t)s1 * 16 + l];
                a1.x = fmaf(w0, r0.x, a1.x); a1.y = fmaf(w0, r0.y, a1.y);
                a1.z = fmaf(w0, r0.z, a1.z); a1.w = fmaf(w0, r0.w, a1.w);
                a2.x = fmaf(w1, r1.x, a2.x); a2.y = fmaf(w1, r1.y, a2.y);
                a2.z = fmaf(w1, r1.z, a2.z); a2.w = fmaf(w1, r1.w, a2.w);
            }
            if (k2 < k2max) {
                int   s0 = __shfl(sB, k2, 16);
                float w0 = __shfl(wB, k2, 16);
                float4 r0 = in4[(size_t)s0 * 16 + l];
                a3.x = fmaf(w0, r0.x, a3.x); a3.y = fmaf(w0, r0.y, a3.y);
                a3.z = fmaf(w0, r0.z, a3.z); a3.w = fmaf(w0, r0.w, a3.w);
            }
        }
    }
    float4 r;
    r.x = dn * ((a0.x + a1.x) + (a2.x + a3.x));
    r.y = dn * ((a0.y + a1.y) + (a2.y + a3.y));
    r.z = dn * ((a0.z + a1.z) + (a2.z + a3.z));
    r.w = dn * ((a0.w + a1.w) + (a2.w + a3.w));
    out4[(size_t)n * 16 + l] = r;
}

// overflow fixup: out[dst] += dinv[dst]*dinv[src]*in[src]  (normally 0 entries)
__global__ void k_ovf(const float4* __restrict__ in4, const int* __restrict__ ovf_n,
                      const int2* __restrict__ ovf, const float* __restrict__ dinv,
                      float* __restrict__ out) {
    int m = *ovf_n;
    if (m > OVF_CAP) m = OVF_CAP;
    int total = m * 16;
    for (int idx = blockIdx.x * blockDim.x + threadIdx.x; idx < total;
         idx += gridDim.x * blockDim.x) {
        int e = idx >> 4, l = idx & 15;
        int2 p = ovf[e];
        float w = dinv[p.x] * dinv[p.y];
        float4 r = in4[(size_t)p.x * 16 + l];
        float* o = &out[(size_t)p.y * D + 4 * l];
        atomicAdd(o + 0, w * r.x);
        atomicAdd(o + 1, w * r.y);
        atomicAdd(o + 2, w * r.z);
        atomicAdd(o + 3, w * r.w);
    }
}

// ======================= linear (in-place safe: row-local) =======================
__global__ __launch_bounds__(256) void k_linear4(const float4* in4,
                                                 const float* __restrict__ W,
                                                 const float* __restrict__ bias,
                                                 float4* out4) {
    __shared__ float4 Wq[64 * 16];     // Wq[i*16+l] = {W[4l+c][i], c=0..3}
    __shared__ float rowbuf[64][68];

    const int tid = threadIdx.x;
    for (int m = tid; m < 64 * 16; m += 256) {
        int i = m >> 4, l = m & 15;
        float4 v;
        v.x = W[(4 * l + 0) * 64 + i];
        v.y = W[(4 * l + 1) * 64 + i];
        v.z = W[(4 * l + 2) * 64 + i];
        v.w = W[(4 * l + 3) * 64 + i];
        Wq[m] = v;
    }
    __syncthreads();

    const int g = tid >> 4;
    const int l = tid & 15;
    const float4 bv = *(const float4*)&bias[4 * l];

    for (int chunk = blockIdx.x; chunk < NCH_LIN; chunk += gridDim.x) {
        const int nb = chunk * 64 + 4 * g;
        const int n0 = nb, n1 = nb + 1, n2 = nb + 2, n3 = nb + 3;
        float4 r0 = in4[(size_t)(n0 < NN ? n0 : NN - 1) * 16 + l];
        float4 r1 = in4[(size_t)(n1 < NN ? n1 : NN - 1) * 16 + l];
        float4 r2 = in4[(size_t)(n2 < NN ? n2 : NN - 1) * 16 + l];
        float4 r3 = in4[(size_t)(n3 < NN ? n3 : NN - 1) * 16 + l];
        *(float4*)&rowbuf[4 * g + 0][4 * l] = r0;
        *(float4*)&rowbuf[4 * g + 1][4 * l] = r1;
        *(float4*)&rowbuf[4 * g + 2][4 * l] = r2;
        *(float4*)&rowbuf[4 * g + 3][4 * l] = r3;

        float4 y0 = bv, y1 = bv, y2 = bv, y3 = bv;
        #pragma unroll
        for (int kq = 0; kq < 16; ++kq) {
            float4 ri0 = *(const float4*)&rowbuf[4 * g + 0][4 * kq];
            float4 ri1 = *(const float4*)&rowbuf[4 * g + 1][4 * kq];
            float4 ri2 = *(const float4*)&rowbuf[4 * g + 2][4 * kq];
            float4 ri3 = *(const float4*)&rowbuf[4 * g + 3][4 * kq];
            float4 wq0 = Wq[(4 * kq + 0) * 16 + l];
            float4 wq1 = Wq[(4 * kq + 1) * 16 + l];
            float4 wq2 = Wq[(4 * kq + 2) * 16 + l];
            float4 wq3 = Wq[(4 * kq + 3) * 16 + l];
            y0.x = fmaf(ri0.x, wq0.x, y0.x); y0.y = fmaf(ri0.x, wq0.y, y0.y);
            y0.z = fmaf(ri0.x, wq0.z, y0.z); y0.w = fmaf(ri0.x, wq0.w, y0.w);
            y0.x = fmaf(ri0.y, wq1.x, y0.x); y0.y = fmaf(ri0.y, wq1.y, y0.y);
            y0.z = fmaf(ri0.y, wq1.z, y0.z); y0.w = fmaf(ri0.y, wq1.w, y0.w);
            y0.x = fmaf(ri0.z, wq2.x, y0.x); y0.y = fmaf(ri0.z, wq2.y, y0.y);
            y0.z = fmaf(ri0.z, wq2.z, y0.z); y0.w = fmaf(ri0.z, wq2.w, y0.w);
            y0.x = fmaf(ri0.w, wq3.x, y0.x); y0.y = fmaf(ri0.w, wq3.y, y0.y);
            y0.z = fmaf(ri0.w, wq3.z, y0.z); y0.w = fmaf(ri0.w, wq3.w, y0.w);

            y1.x = fmaf(ri1.x, wq0.x, y1.x); y1.y = fmaf(ri1.x, wq0.y, y1.y);
            y1.z = fmaf(ri1.x, wq0.z, y1.z); y1.w = fmaf(ri1.x, wq0.w, y1.w);
            y1.x = fmaf(ri1.y, wq1.x, y1.x); y1.y = fmaf(ri1.y, wq1.y, y1.y);
            y1.z = fmaf(ri1.y, wq1.z, y1.z); y1.w = fmaf(ri1.y, wq1.w, y1.w);
            y1.x = fmaf(ri1.z, wq2.x, y1.x); y1.y = fmaf(ri1.z, wq2.y, y1.y);
            y1.z = fmaf(ri1.z, wq2.z, y1.z); y1.w = fmaf(ri1.z, wq2.w, y1.w);
            y1.x = fmaf(ri1.w, wq3.x, y1.x); y1.y = fmaf(ri1.w, wq3.y, y1.y);
            y1.z = fmaf(ri1.w, wq3.z, y1.z); y1.w = fmaf(ri1.w, wq3.w, y1.w);

            y2.x = fmaf(ri2.x, wq0.x, y2.x); y2.y = fmaf(ri2.x, wq0.y, y2.y);
            y2.z = fmaf(ri2.x, wq0.z, y2.z); y2.w = fmaf(ri2.x, wq0.w, y2.w);
            y2.x = fmaf(ri2.y, wq1.x, y2.x); y2.y = fmaf(ri2.y, wq1.y, y2.y);
            y2.z = fmaf(ri2.y, wq1.z, y2.z); y2.w = fmaf(ri2.y, wq1.w, y2.w);
            y2.x = fmaf(ri2.z, wq2.x, y2.x); y2.y = fmaf(ri2.z, wq2.y, y2.y);
            y2.z = fmaf(ri2.z, wq2.z, y2.z); y2.w = fmaf(ri2.z, wq2.w, y2.w);
            y2.x = fmaf(ri2.w, wq3.x, y2.x); y2.y = fmaf(ri2.w, wq3.y, y2.y);
            y2.z = fmaf(ri2.w, wq3.z, y2.z); y2.w = fmaf(ri2.w, wq3.w, y2.w);

            y3.x = fmaf(ri3.x, wq0.x, y3.x); y3.y = fmaf(ri3.x, wq0.y, y3.y);
            y3.z = fmaf(ri3.x, wq0.z, y3.z); y3.w = fmaf(ri3.x, wq0.w, y3.w);
            y3.x = fmaf(ri3.y, wq1.x, y3.x); y3.y = fmaf(ri3.y, wq1.y, y3.y);
            y3.z = fmaf(ri3.y, wq1.z, y3.z); y3.w = fmaf(ri3.y, wq1.w, y3.w);
            y3.x = fmaf(ri3.z, wq2.x, y3.x); y3.y = fmaf(ri3.z, wq2.y, y3.y);
            y3.z = fmaf(ri3.z, wq2.z, y3.z); y3.w = fmaf(ri3.z, wq2.w, y3.w);
            y3.x = fmaf(ri3.w, wq3.x, y3.x); y3.y = fmaf(ri3.w, wq3.y, y3.y);
            y3.z = fmaf(ri3.w, wq3.z, y3.z); y3.w = fmaf(ri3.w, wq3.w, y3.w);
        }
        if (n0 < NN) out4[(size_t)n0 * 16 + l] = y0;
        if (n1 < NN) out4[(size_t)n1 * 16 + l] = y1;
        if (n2 < NN) out4[(size_t)n2 * 16 + l] = y2;
        if (n3 < NN) out4[(size_t)n3 * 16 + l] = y3;
    }
}

// ======================= fallback path (atomic scatter, round-1) =======================

__global__ void k_init_deg(float* __restrict__ deg) {
    int n = blockIdx.x * blockDim.x + threadIdx.x;
    if (n < NN) deg[n] = 1.0f;
}
__global__ void k_count_deg(const int* __restrict__ dst, float* __restrict__ deg) {
    int e = blockIdx.x * blockDim.x + threadIdx.x;
    if (e < NE) atomicAdd(&deg[dst[e]], 1.0f);
}
__global__ void k_dinv_f(float* __restrict__ deg) {
    int n = blockIdx.x * blockDim.x + threadIdx.x;
    if (n < NN) deg[n] = rsqrtf(deg[n]);
}
__global__ void k_prop_init(const float* __restrict__ in, const float* __restrict__ dinv,
                            float* __restrict__ out) {
    int i = blockIdx.x * blockDim.x + threadIdx.x;
    if (i < NN * D) {
        int n = i >> 6;
        float di = dinv[n];
        out[i] = di * di * in[i];
    }
}
__global__ __launch_bounds__(256) void k_prop_edges(const float* __restrict__ in,
                                                    const int* __restrict__ src,
                                                    const int* __restrict__ dst,
                                                    const float* __restrict__ dinv,
                                                    float* __restrict__ out) {
    int t = blockIdx.x * blockDim.x + threadIdx.x;
    int e = t >> 6, f = t & 63;
    if (e < NE) {
        int s = src[e], d = dst[e];
        float w = dinv[s] * dinv[d];
        atomicAdd(&out[d * D + f], w * in[s * D + f]);
    }
}
__global__ __launch_bounds__(256) void k_linear(const float* __restrict__ in,
                                                const float* __restrict__ W,
                                                const float* __restrict__ bias,
                                                float* __restrict__ out) {
    __shared__ float Wt[64 * 65];
    __shared__ float rows[4][64];
    const int tid = threadIdx.x;
    for (int m = tid; m < 64 * 64; m += 256) {
        int o = m >> 6, i = m & 63;
        Wt[i * 65 + o] = W[m];
    }
    __syncthreads();
    const int wave = tid >> 6, lane = tid & 63;
    const float bo = bias[lane];
    for (int base = blockIdx.x * 4; base < NN; base += gridDim.x * 4) {
        int n = base + wave;
        if (n < NN) {
            rows[wave][lane] = in[n * D + lane];
            float acc = bo;
            #pragma unroll
            for (int i = 0; i < 64; ++i)
                acc = fmaf(rows[wave][i], Wt[i * 65 + lane], acc);
            out[n * D + lane] = acc;
        }
    }
}

// ======================= launch =======================

extern "C" void kernel_launch(void* const* d_in, const int* in_sizes, int n_in,
                              void* d_out, int out_size, void* d_ws, size_t ws_size,
                              hipStream_t stream) {
    const float* x   = (const float*)d_in[0];
    const int*   ei  = (const int*)d_in[1];
    const float* W   = (const float*)d_in[2];
    const float* b   = (const float*)d_in[3];
    float* out = (float*)d_out;

    const int* src = ei;        // edge_index[0]
    const int* dst = ei + NE;   // edge_index[1]

    char* ws = (char*)d_ws;
    size_t off = 0;
    auto take = [&](size_t bytes) -> char* {
        char* p = ws + off;
        off = (off + bytes + 255) & ~(size_t)255;
        return p;
    };

    int*   cnt    = (int*)take((size_t)NN * 4);
    float* dinv   = (float*)take((size_t)NN * 4);
    int*   ovf_n  = (int*)take(256);
    int2*  ovf    = (int2*)take((size_t)OVF_CAP * 8);
    float* buf    = (float*)take((size_t)NN * D * 4);
    int*   bucket = (int*)take((size_t)NN * CAP * 4);
    const bool use_bucket = (off <= ws_size);

    const int B = 256;
    const int gridE1 = (NE + B - 1) / B;   // 3907
    const int gridN1 = (NN + B - 1) / B;   // 391
    const int gridNW = NN / 16;            // 6250

    if (use_bucket) {
        hipMemsetAsync(cnt, 0, (size_t)NN * 4, stream);
        hipMemsetAsync(ovf_n, 0, 4, stream);
        k_fill_bucket<<<gridE1, B, 0, stream>>>(src, dst, cnt, bucket, ovf_n, ovf);
        k_dinv<<<gridN1, B, 0, stream>>>(cnt, dinv);

        const float4* x4   = (const float4*)x;
        float4*       out4 = (float4*)out;
        float4*       buf4 = (float4*)buf;
        // hop1: x -> out
        k_gather32<<<gridNW, B, 0, stream>>>(x4, cnt, bucket, dinv, out4);
        k_ovf<<<32, B, 0, stream>>>(x4, ovf_n, ovf, dinv, (float*)out4);
        // hop2: out -> buf
        k_gather32<<<gridNW, B, 0, stream>>>((const float4*)out4, cnt, bucket, dinv, buf4);
        k_ovf<<<32, B, 0, stream>>>((const float4*)out4, ovf_n, ovf, dinv, (float*)buf4);
        // hop3: buf -> out
        k_gather32<<<gridNW, B, 0, stream>>>((const float4*)buf4, cnt, bucket, dinv, out4);
        k_ovf<<<32, B, 0, stream>>>((const float4*)buf4, ovf_n, ovf, dinv, (float*)out4);
        // linear in-place
        k_linear4<<<1024, B, 0, stream>>>((const float4*)out4, W, b, out4);
    } else {
        const int gridF = (NN * D + B - 1) / B;
        const int gridEW = (NE * 64) / B;
        k_init_deg <<<gridN1, B, 0, stream>>>(dinv);
        k_count_deg<<<gridE1, B, 0, stream>>>(dst, dinv);
        k_dinv_f   <<<gridN1, B, 0, stream>>>(dinv);
        k_prop_init <<<gridF, B, 0, stream>>>(x, dinv, buf);
        k_prop_edges<<<gridEW, B, 0, stream>>>(x, src, dst, dinv, buf);
        k_prop_init <<<gridF, B, 0, stream>>>(buf, dinv, out);
        k_prop_edges<<<gridEW, B, 0, stream>>>(buf, src, dst, dinv, out);
        k_prop_init <<<gridF, B, 0, stream>>>(out, dinv, buf);
        k_prop_edges<<<gridEW, B, 0, stream>>>(out, src, dst, dinv, buf);
        k_linear<<<NN / 4, B, 0, stream>>>(buf, W, b, out);
    }
}